// Round 1
// baseline (4676.122 us; speedup 1.0000x reference)
//
#include <hip/hip_runtime.h>
#include <math.h>

// Problem constants: B=8, N=1024, C=576, 6 cross blocks.
#define LN_EPS 1e-5f

enum { EP_STORE = 0, EP_SIG = 1, EP_BIAS = 2, EP_BIAS_RES = 3, EP_ACCUM = 4 };

// Generic tiled fp32 GEMM: C[m,n] = sum_k A[m,k] * B'[k,n]
//   TRANSB=true : B is [N,K] row-major (B'[k,n] = B[n,k])   ("NT")
//   TRANSB=false: B is [K,N] row-major                      ("NN")
// 64x64 tile, TK=16, 256 threads, 4x4 micro-tile per thread.
// All of M,N multiples of 64 and K multiple of 16 (true for every call here).
template <int EP, bool TRANSB>
__global__ __launch_bounds__(256) void gemm64(
    const float* __restrict__ A, const float* __restrict__ B,
    float* __restrict__ C, const float* __restrict__ bias,
    const float* __restrict__ res, int lda, int ldb, int ldc, int K,
    long sA, long sB, long sC, float scale) {
  __shared__ float As[16][68];  // [k][m], +4 pad keeps float4 alignment, 2-way max on write
  __shared__ float Bs[16][68];  // [k][n]

  const int tid = threadIdx.x;
  const int tx = tid & 15;        // output col group
  const int ty = tid >> 4;        // output row group
  const int bm = blockIdx.y << 6;
  const int bn = blockIdx.x << 6;

  A += (long)blockIdx.z * sA;
  B += (long)blockIdx.z * sB;
  C += (long)blockIdx.z * sC;

  // loader indices (NT style: row = tid/4, 4 contiguous k's)
  const int lm = tid >> 2;            // 0..63
  const int lk = (tid & 3) << 2;      // 0,4,8,12
  // loader indices (NN B: k-row = tid/16, 4 contiguous n's)
  const int lkb = tid >> 4;           // 0..15
  const int lnb = (tid & 15) << 2;    // 0..60

  float acc[4][4];
#pragma unroll
  for (int i = 0; i < 4; ++i)
#pragma unroll
    for (int j = 0; j < 4; ++j) acc[i][j] = 0.f;

  for (int k0 = 0; k0 < K; k0 += 16) {
    const float4 av =
        *reinterpret_cast<const float4*>(A + (long)(bm + lm) * lda + k0 + lk);
    float4 bv;
    if (TRANSB)
      bv = *reinterpret_cast<const float4*>(B + (long)(bn + lm) * ldb + k0 + lk);
    else
      bv = *reinterpret_cast<const float4*>(B + (long)(k0 + lkb) * ldb + bn + lnb);

    __syncthreads();  // protect LDS from previous iteration's readers
    As[lk + 0][lm] = av.x;
    As[lk + 1][lm] = av.y;
    As[lk + 2][lm] = av.z;
    As[lk + 3][lm] = av.w;
    if (TRANSB) {
      Bs[lk + 0][lm] = bv.x;
      Bs[lk + 1][lm] = bv.y;
      Bs[lk + 2][lm] = bv.z;
      Bs[lk + 3][lm] = bv.w;
    } else {
      *reinterpret_cast<float4*>(&Bs[lkb][lnb]) = bv;
    }
    __syncthreads();

#pragma unroll
    for (int kk = 0; kk < 16; ++kk) {
      const float4 a4 = *reinterpret_cast<const float4*>(&As[kk][ty << 2]);
      const float4 b4 = *reinterpret_cast<const float4*>(&Bs[kk][tx << 2]);
      const float ar[4] = {a4.x, a4.y, a4.z, a4.w};
      const float br[4] = {b4.x, b4.y, b4.z, b4.w};
#pragma unroll
      for (int i = 0; i < 4; ++i)
#pragma unroll
        for (int j = 0; j < 4; ++j) acc[i][j] = fmaf(ar[i], br[j], acc[i][j]);
    }
  }

  // epilogue: one float4 store per micro-row
  float4 bb;
  if (EP == EP_BIAS || EP == EP_BIAS_RES)
    bb = *reinterpret_cast<const float4*>(bias + bn + (tx << 2));
#pragma unroll
  for (int i = 0; i < 4; ++i) {
    const long row = bm + (ty << 2) + i;
    const long idx = row * (long)ldc + bn + (tx << 2);
    float4 r;
    r.x = acc[i][0];
    r.y = acc[i][1];
    r.z = acc[i][2];
    r.w = acc[i][3];
    if (EP == EP_SIG) {
      r.x = 1.f / (1.f + expf(-r.x * scale));
      r.y = 1.f / (1.f + expf(-r.y * scale));
      r.z = 1.f / (1.f + expf(-r.z * scale));
      r.w = 1.f / (1.f + expf(-r.w * scale));
    } else if (EP == EP_BIAS || EP == EP_BIAS_RES) {
      r.x += bb.x;
      r.y += bb.y;
      r.z += bb.z;
      r.w += bb.w;
      if (EP == EP_BIAS_RES) {
        const float4 rr = *reinterpret_cast<const float4*>(res + idx);
        r.x += rr.x;
        r.y += rr.y;
        r.z += rr.z;
        r.w += rr.w;
      }
    } else if (EP == EP_ACCUM) {
      const float4 cc = *reinterpret_cast<const float4*>(C + idx);
      r.x += cc.x;
      r.y += cc.y;
      r.z += cc.z;
      r.w += cc.w;
    }
    *reinterpret_cast<float4*>(C + idx) = r;
  }
}

// LayerNorm over last dim C=576: one block (576 threads, 9 waves) per row.
__global__ __launch_bounds__(576) void ln576(const float* __restrict__ x,
                                             const float* __restrict__ g,
                                             const float* __restrict__ b,
                                             float* __restrict__ out) {
  __shared__ float red[2][9];
  __shared__ float mu_s, rs_s;
  const long row = blockIdx.x;
  const int t = threadIdx.x;
  const float v = x[row * 576 + t];
  float s = v, s2 = v * v;
#pragma unroll
  for (int off = 32; off > 0; off >>= 1) {
    s += __shfl_xor(s, off);
    s2 += __shfl_xor(s2, off);
  }
  const int w = t >> 6;
  if ((t & 63) == 0) {
    red[0][w] = s;
    red[1][w] = s2;
  }
  __syncthreads();
  if (t == 0) {
    float a = 0.f, a2 = 0.f;
#pragma unroll
    for (int i = 0; i < 9; ++i) {
      a += red[0][i];
      a2 += red[1][i];
    }
    const float mu = a * (1.f / 576.f);
    const float var = a2 * (1.f / 576.f) - mu * mu;
    mu_s = mu;
    rs_s = rsqrtf(var + LN_EPS);
  }
  __syncthreads();
  out[row * 576 + t] = (v - mu_s) * rs_s * g[t] + b[t];
}

// exact GELU: 0.5*x*(1+erf(x/sqrt(2)))
__global__ __launch_bounds__(256) void gelu_k(const float* __restrict__ in,
                                              float* __restrict__ out, long n) {
  long i = (long)blockIdx.x * blockDim.x + threadIdx.x;
  const long stride = (long)gridDim.x * blockDim.x;
  for (; i < n; i += stride) {
    const float x = in[i];
    out[i] = 0.5f * x * (1.f + erff(x * 0.70710678118654752f));
  }
}

extern "C" void kernel_launch(void* const* d_in, const int* in_sizes, int n_in,
                              void* d_out, int out_size, void* d_ws,
                              size_t ws_size, hipStream_t stream) {
  const float* img = (const float*)d_in[0];
  const float* aolp = (const float*)d_in[1];
  const float* dolp = (const float*)d_in[2];
  const float* lnx_g = (const float*)d_in[3];
  const float* lnx_b = (const float*)d_in[4];
  const float* lny_g = (const float*)d_in[5];
  const float* lny_b = (const float*)d_in[6];
  const float* lnz_g = (const float*)d_in[7];
  const float* lnz_b = (const float*)d_in[8];
  const float* Wq = (const float*)d_in[9];
  const float* Wk = (const float*)d_in[10];
  const float* Wv = (const float*)d_in[11];
  const float* Wp = (const float*)d_in[12];
  const float* bp = (const float*)d_in[13];
  const float* Wf = (const float*)d_in[14];
  const float* bf = (const float*)d_in[15];
  float* out = (float*)d_out;
  float* ws = (float*)d_ws;

  const long S = 8L * 1024 * 576;  // one [B,N,C] fp32 tensor (4,718,592 elems)
  float* xn = ws;
  float* yn = ws + S;
  float* q = ws + 2 * S;
  float* k = ws + 3 * S;
  float* v = ws + 4 * S;
  float* o = ws + 5 * S;
  float* sbuf = ws + 6 * S;              // [8,1024,1024] scores
  float* fused = sbuf + 8L * 1024 * 1024;  // [B,N,C] accumulator
  // total ws use: 7*S + 8M floats = ~166 MB

  const float* src[3] = {img, aolp, dolp};
  const int xi[6] = {0, 0, 1, 1, 2, 2};
  const int yi[6] = {1, 2, 0, 2, 0, 1};
  const float scale = 1.f / 24.f;  // 576^-0.5

  const dim3 blk(256);
  const dim3 gProj(9, 128, 1);   // M=8192, N=576
  const dim3 gScore(16, 16, 8);  // M=N=1024, batched over B
  const dim3 gAV(9, 16, 8);      // M=1024, N=576, batched over B

  for (int i = 0; i < 6; ++i) {
    const float* X = src[xi[i]];
    const float* Y = src[yi[i]];
    const long wOff = (long)i * 576 * 576;

    ln576<<<8192, 576, 0, stream>>>(X, lnx_g + i * 576, lnx_b + i * 576, xn);
    ln576<<<8192, 576, 0, stream>>>(Y, lny_g + i * 576, lny_b + i * 576, yn);

    // q = yn @ Wq_i^T ; k,v = xn @ {Wk,Wv}_i^T
    gemm64<EP_STORE, true><<<gProj, blk, 0, stream>>>(
        yn, Wq + wOff, q, nullptr, nullptr, 576, 576, 576, 576, 0, 0, 0, 0.f);
    gemm64<EP_STORE, true><<<gProj, blk, 0, stream>>>(
        xn, Wk + wOff, k, nullptr, nullptr, 576, 576, 576, 576, 0, 0, 0, 0.f);
    gemm64<EP_STORE, true><<<gProj, blk, 0, stream>>>(
        xn, Wv + wOff, v, nullptr, nullptr, 576, 576, 576, 576, 0, 0, 0, 0.f);

    // s = sigmoid(q @ k^T * scale), per batch
    gemm64<EP_SIG, true><<<gScore, blk, 0, stream>>>(
        q, k, sbuf, nullptr, nullptr, 576, 576, 1024, 576, 1024L * 576,
        1024L * 576, 1024L * 1024, scale);

    // o = s @ v, per batch (NN)
    gemm64<EP_STORE, false><<<gAV, blk, 0, stream>>>(
        sbuf, v, o, nullptr, nullptr, 1024, 576, 576, 1024, 1024L * 1024,
        1024L * 576, 1024L * 576, 0.f);

    // t = o @ Wp_i^T + bp_i + xn  -> reuse yn
    gemm64<EP_BIAS_RES, true><<<gProj, blk, 0, stream>>>(
        o, Wp + wOff, yn, bp + i * 576, xn, 576, 576, 576, 576, 0, 0, 0, 0.f);

    // z = LN(t) -> reuse q
    ln576<<<8192, 576, 0, stream>>>(yn, lnz_g + i * 576, lnz_b + i * 576, q);

    // fused (+)= z @ Wf[:, i*576:(i+1)*576]^T  (+ bf on first block)
    if (i == 0)
      gemm64<EP_BIAS, true><<<gProj, blk, 0, stream>>>(
          q, Wf + i * 576, fused, bf, nullptr, 576, 3456, 576, 576, 0, 0, 0,
          0.f);
    else
      gemm64<EP_ACCUM, true><<<gProj, blk, 0, stream>>>(
          q, Wf + i * 576, fused, nullptr, nullptr, 576, 3456, 576, 576, 0, 0,
          0, 0.f);
  }

  gelu_k<<<2048, 256, 0, stream>>>(fused, out, S);
}

// Round 2
// 2187.269 us; speedup vs baseline: 2.1379x; 2.1379x over previous
//
#include <hip/hip_runtime.h>
#include <math.h>

#define LN_EPS 1e-5f

typedef short s8v __attribute__((ext_vector_type(8)));
typedef float f4v __attribute__((ext_vector_type(4)));

__device__ __forceinline__ short f2bf(float x) {
  union { float f; unsigned u; } v; v.f = x;
  const unsigned r = v.u + 0x7fffu + ((v.u >> 16) & 1u);
  return (short)(r >> 16);
}
__device__ __forceinline__ float bf2f(short s) {
  union { unsigned u; float f; } v;
  v.u = ((unsigned)(unsigned short)s) << 16;
  return v.f;
}

__device__ __forceinline__ void gld16(const void* g, void* l) {
  __builtin_amdgcn_global_load_lds(
      (const __attribute__((address_space(1))) void*)g,
      (__attribute__((address_space(3))) void*)l, 16, 0, 0);
}

enum { EP_SPLIT = 0, EP_SPLIT_T, EP_SIG, EP_RES, EP_BIAS, EP_ACC, EP_ACCGELU };

// Split-bf16 NT GEMM: C = A * B^T, A[M][K], B[N][K], both given as hi/lo bf16.
// 3-term MFMA per fragment (hi*hi + hi*lo + lo*hi) ~= fp32 precision.
// BM=128, BN=64*WC, BK=64, waves = 2*WC (wave-tile 64x64, 4x4 frags of 16x16x32).
// LDS rows are 128B; chunk16 index XOR (row&7) bank-swizzle applied on the
// global SOURCE address during global_load_lds staging (linear LDS dest) and
// again on the ds_read side (same involution) -> conflict-free frag reads.
template <int EP, int WC>
__global__ __launch_bounds__(128 * WC) void gemmk(
    const short* __restrict__ Ah, const short* __restrict__ Al,
    const short* __restrict__ Bh, const short* __restrict__ Bl,
    short* __restrict__ Ch, short* __restrict__ Cl, float* __restrict__ Cf,
    const float* __restrict__ bias, const short* __restrict__ resH,
    const short* __restrict__ resL, float* __restrict__ out2, int lda, int ldb,
    int ldc, int K, long sA, long sB, long sC, float scale) {
  constexpr int BM = 128, BN = 64 * WC, T = 128 * WC;
  constexpr int RA = (BM * 128) / (T * 16);  // 16B rounds per A tensor
  constexpr int RB = (BN * 128) / (T * 16);
  __shared__ short lds[(2 * BM + 2 * BN) * 64];
  short* AsH = lds;
  short* AsL = lds + BM * 64;
  short* BsH = lds + 2 * BM * 64;
  short* BsL = lds + 2 * BM * 64 + BN * 64;

  const int tid = threadIdx.x;
  const int lane = tid & 63;
  const int wave = tid >> 6;
  const int wr = wave / WC;       // 0..1
  const int wc = wave % WC;       // 0..WC-1
  const int half = lane >> 4;     // 0..3
  const int l15 = lane & 15;
  const int bm = blockIdx.y * BM;
  const int bn = blockIdx.x * BN;
  const long zb = blockIdx.z;

  Ah += zb * sA; Al += zb * sA;
  Bh += zb * sB; Bl += zb * sB;

  f4v acc[4][4];
#pragma unroll
  for (int i = 0; i < 4; ++i)
#pragma unroll
    for (int j = 0; j < 4; ++j)
#pragma unroll
      for (int r = 0; r < 4; ++r) acc[i][j][r] = 0.f;

  for (int k0 = 0; k0 < K; k0 += 64) {
    __syncthreads();
#pragma unroll
    for (int t = 0; t < RA; ++t) {
      const int off = (t * T + tid) * 16;  // byte offset in [BM][128B] tile
      const int row = off >> 7;
      const int ke = ((((off >> 4) & 7) ^ (row & 7)) << 3);  // swizzled k-chunk
      const long ga = (long)(bm + row) * lda + k0 + ke;
      gld16(Ah + ga, (char*)AsH + off);
      gld16(Al + ga, (char*)AsL + off);
    }
#pragma unroll
    for (int t = 0; t < RB; ++t) {
      const int off = (t * T + tid) * 16;
      const int row = off >> 7;
      const int ke = ((((off >> 4) & 7) ^ (row & 7)) << 3);
      const long gb = (long)(bn + row) * ldb + k0 + ke;
      gld16(Bh + gb, (char*)BsH + off);
      gld16(Bl + gb, (char*)BsL + off);
    }
    __syncthreads();

#pragma unroll
    for (int s = 0; s < 2; ++s) {
      s8v ah[4], al[4], bh[4], bl[4];
#pragma unroll
      for (int i = 0; i < 4; ++i) {
        const int r = wr * 64 + i * 16 + l15;
        const int ad = r * 64 + ((((s << 2) + half) ^ (r & 7)) << 3);
        ah[i] = *(const s8v*)&AsH[ad];
        al[i] = *(const s8v*)&AsL[ad];
      }
#pragma unroll
      for (int j = 0; j < 4; ++j) {
        const int c = wc * 64 + j * 16 + l15;
        const int bd = c * 64 + ((((s << 2) + half) ^ (c & 7)) << 3);
        bh[j] = *(const s8v*)&BsH[bd];
        bl[j] = *(const s8v*)&BsL[bd];
      }
#pragma unroll
      for (int i = 0; i < 4; ++i)
#pragma unroll
        for (int j = 0; j < 4; ++j) {
          acc[i][j] = __builtin_amdgcn_mfma_f32_16x16x32_bf16(ah[i], bh[j],
                                                              acc[i][j], 0, 0, 0);
          acc[i][j] = __builtin_amdgcn_mfma_f32_16x16x32_bf16(ah[i], bl[j],
                                                              acc[i][j], 0, 0, 0);
          acc[i][j] = __builtin_amdgcn_mfma_f32_16x16x32_bf16(al[i], bh[j],
                                                              acc[i][j], 0, 0, 0);
        }
    }
  }

  // Epilogue. D frag: col = lane&15, row = (lane>>4)*4 + reg (m89-verified).
#pragma unroll
  for (int i = 0; i < 4; ++i) {
#pragma unroll
    for (int r = 0; r < 4; ++r) {
      const int row = bm + wr * 64 + i * 16 + half * 4 + r;
#pragma unroll
      for (int j = 0; j < 4; ++j) {
        const int col = bn + wc * 64 + j * 16 + l15;
        float x = acc[i][j][r];
        if (EP == EP_SPLIT) {
          const long idx = zb * sC + (long)row * ldc + col;
          const short h = f2bf(x);
          Ch[idx] = h;
          Cl[idx] = f2bf(x - bf2f(h));
        } else if (EP == EP_SPLIT_T) {
          // v-projection: write transposed vt[b][col][tok], row = b*1024+tok
          const long idx = ((long)(row >> 10) * 576 + col) * 1024 + (row & 1023);
          const short h = f2bf(x);
          Ch[idx] = h;
          Cl[idx] = f2bf(x - bf2f(h));
        } else if (EP == EP_SIG) {
          x = 1.f / (1.f + expf(-x * scale));
          const long idx = zb * sC + (long)row * ldc + col;
          const short h = f2bf(x);
          Ch[idx] = h;
          Cl[idx] = f2bf(x - bf2f(h));
        } else if (EP == EP_RES) {
          const long idx = (long)row * ldc + col;
          Cf[idx] = x + bias[col] + bf2f(resH[idx]) + bf2f(resL[idx]);
        } else if (EP == EP_BIAS) {
          const long idx = (long)row * ldc + col;
          Cf[idx] = x + bias[col];
        } else if (EP == EP_ACC) {
          const long idx = (long)row * ldc + col;
          Cf[idx] += x;
        } else if (EP == EP_ACCGELU) {
          const long idx = (long)row * ldc + col;
          const float sum = Cf[idx] + x;
          out2[idx] = 0.5f * sum * (1.f + erff(sum * 0.70710678118654752f));
        }
      }
    }
  }
}

// LayerNorm over C=576, writes hi/lo bf16 split. One 576-thread block per row.
__global__ __launch_bounds__(576) void ln576(const float* __restrict__ x,
                                             const float* __restrict__ g,
                                             const float* __restrict__ b,
                                             short* __restrict__ oh,
                                             short* __restrict__ ol) {
  __shared__ float red[2][9];
  __shared__ float mu_s, rs_s;
  const long row = blockIdx.x;
  const int t = threadIdx.x;
  const float v = x[row * 576 + t];
  float s = v, s2 = v * v;
#pragma unroll
  for (int off = 32; off > 0; off >>= 1) {
    s += __shfl_xor(s, off);
    s2 += __shfl_xor(s2, off);
  }
  if ((t & 63) == 0) {
    red[0][t >> 6] = s;
    red[1][t >> 6] = s2;
  }
  __syncthreads();
  if (t == 0) {
    float a = 0.f, a2 = 0.f;
#pragma unroll
    for (int i = 0; i < 9; ++i) {
      a += red[0][i];
      a2 += red[1][i];
    }
    const float mu = a * (1.f / 576.f);
    mu_s = mu;
    rs_s = rsqrtf(a2 * (1.f / 576.f) - mu * mu + LN_EPS);
  }
  __syncthreads();
  const float y = (v - mu_s) * rs_s * g[t] + b[t];
  const short h = f2bf(y);
  oh[row * 576 + t] = h;
  ol[row * 576 + t] = f2bf(y - bf2f(h));
}

// fp32 -> (hi,lo) bf16 split, elementwise.
__global__ __launch_bounds__(256) void splitk(const float* __restrict__ in,
                                              short* __restrict__ oh,
                                              short* __restrict__ ol, long n) {
  long i = (long)blockIdx.x * blockDim.x + threadIdx.x;
  const long stride = (long)gridDim.x * blockDim.x;
  for (; i < n; i += stride) {
    const float x = in[i];
    const short h = f2bf(x);
    oh[i] = h;
    ol[i] = f2bf(x - bf2f(h));
  }
}

extern "C" void kernel_launch(void* const* d_in, const int* in_sizes, int n_in,
                              void* d_out, int out_size, void* d_ws,
                              size_t ws_size, hipStream_t stream) {
  const float* img = (const float*)d_in[0];
  const float* aolp = (const float*)d_in[1];
  const float* dolp = (const float*)d_in[2];
  const float* lnx_g = (const float*)d_in[3];
  const float* lnx_b = (const float*)d_in[4];
  const float* lny_g = (const float*)d_in[5];
  const float* lny_b = (const float*)d_in[6];
  const float* lnz_g = (const float*)d_in[7];
  const float* lnz_b = (const float*)d_in[8];
  const float* Wq = (const float*)d_in[9];
  const float* Wk = (const float*)d_in[10];
  const float* Wv = (const float*)d_in[11];
  const float* Wp = (const float*)d_in[12];
  const float* bp = (const float*)d_in[13];
  const float* Wf = (const float*)d_in[14];
  const float* bf = (const float*)d_in[15];
  float* out = (float*)d_out;

  const long S = 8L * 1024 * 576;   // 4,718,592
  const long W = 6L * 576 * 576;    // 1,990,656 (also == 576*3456)
  char* p = (char*)d_ws;
  auto alloc = [&](long bytes) {
    char* r = p;
    p += (bytes + 255) & ~255L;
    return r;
  };
  short* xn_h = (short*)alloc(S * 2);
  short* xn_l = (short*)alloc(S * 2);
  short* yn_h = (short*)alloc(S * 2);  // also o after AV
  short* yn_l = (short*)alloc(S * 2);
  short* q_h = (short*)alloc(S * 2);   // also z after LNz
  short* q_l = (short*)alloc(S * 2);
  short* k_h = (short*)alloc(S * 2);
  short* k_l = (short*)alloc(S * 2);
  short* vt_h = (short*)alloc(S * 2);  // [8][576][1024]
  short* vt_l = (short*)alloc(S * 2);
  short* attn_h = (short*)alloc(8L * 1024 * 1024 * 2 * 2);  // hi then lo
  short* attn_l = attn_h + 8L * 1024 * 1024;
  float* t_f32 = (float*)attn_h;  // aliases attn (dead after AV); 18.9<=33.5MB
  float* fused = (float*)alloc(S * 4);
  short* wq_h = (short*)alloc(W * 2);
  short* wq_l = (short*)alloc(W * 2);
  short* wk_h = (short*)alloc(W * 2);
  short* wk_l = (short*)alloc(W * 2);
  short* wv_h = (short*)alloc(W * 2);
  short* wv_l = (short*)alloc(W * 2);
  short* wp_h = (short*)alloc(W * 2);
  short* wp_l = (short*)alloc(W * 2);
  short* wf_h = (short*)alloc(W * 2);
  short* wf_l = (short*)alloc(W * 2);

  // weight splits (re-done every call; ws is re-poisoned)
  splitk<<<1024, 256, 0, stream>>>(Wq, wq_h, wq_l, W);
  splitk<<<1024, 256, 0, stream>>>(Wk, wk_h, wk_l, W);
  splitk<<<1024, 256, 0, stream>>>(Wv, wv_h, wv_l, W);
  splitk<<<1024, 256, 0, stream>>>(Wp, wp_h, wp_l, W);
  splitk<<<1024, 256, 0, stream>>>(Wf, wf_h, wf_l, W);

  const float* src[3] = {img, aolp, dolp};
  const int xi[6] = {0, 0, 1, 1, 2, 2};
  const int yi[6] = {1, 2, 0, 2, 0, 1};
  const float scale = 1.f / 24.f;  // 576^-0.5

  const dim3 gProj(9, 64, 1);    // M=8192 (BM=128), N=576 (BN=64)
  const dim3 gScore(8, 8, 8);    // M=N=1024 (BM=128,BN=128), batch B
  const dim3 gAV(9, 8, 8);       // M=1024, N=576, batch B

  for (int z = 0; z < 6; ++z) {
    const long wo = (long)z * 576 * 576;
    ln576<<<8192, 576, 0, stream>>>(src[xi[z]], lnx_g + z * 576,
                                    lnx_b + z * 576, xn_h, xn_l);
    ln576<<<8192, 576, 0, stream>>>(src[yi[z]], lny_g + z * 576,
                                    lny_b + z * 576, yn_h, yn_l);
    // q = LN(y) @ Wq^T   k = LN(x) @ Wk^T   vt = (LN(x) @ Wv^T)^T
    gemmk<EP_SPLIT, 1><<<gProj, 128, 0, stream>>>(
        yn_h, yn_l, wq_h + wo, wq_l + wo, q_h, q_l, nullptr, nullptr, nullptr,
        nullptr, nullptr, 576, 576, 576, 576, 0, 0, 0, 0.f);
    gemmk<EP_SPLIT, 1><<<gProj, 128, 0, stream>>>(
        xn_h, xn_l, wk_h + wo, wk_l + wo, k_h, k_l, nullptr, nullptr, nullptr,
        nullptr, nullptr, 576, 576, 576, 576, 0, 0, 0, 0.f);
    gemmk<EP_SPLIT_T, 1><<<gProj, 128, 0, stream>>>(
        xn_h, xn_l, wv_h + wo, wv_l + wo, vt_h, vt_l, nullptr, nullptr, nullptr,
        nullptr, nullptr, 576, 576, 0, 576, 0, 0, 0, 0.f);
    // attn = sigmoid(q @ k^T * scale), per batch
    gemmk<EP_SIG, 2><<<gScore, 256, 0, stream>>>(
        q_h, q_l, k_h, k_l, attn_h, attn_l, nullptr, nullptr, nullptr, nullptr,
        nullptr, 576, 576, 1024, 576, 1024L * 576, 1024L * 576, 1024L * 1024,
        scale);
    // o = attn @ vt^T, per batch (into yn buffers)
    gemmk<EP_SPLIT, 1><<<gAV, 128, 0, stream>>>(
        attn_h, attn_l, vt_h, vt_l, yn_h, yn_l, nullptr, nullptr, nullptr,
        nullptr, nullptr, 1024, 1024, 576, 1024, 1024L * 1024, 576L * 1024,
        1024L * 576, 0.f);
    // t = o @ Wp^T + bp + xn  (fp32, into attn-aliased buffer)
    gemmk<EP_RES, 1><<<gProj, 128, 0, stream>>>(
        yn_h, yn_l, wp_h + wo, wp_l + wo, nullptr, nullptr, t_f32, bp + z * 576,
        xn_h, xn_l, nullptr, 576, 576, 576, 576, 0, 0, 0, 0.f);
    // zn = LN(t) (into q buffers)
    ln576<<<8192, 576, 0, stream>>>(t_f32, lnz_g + z * 576, lnz_b + z * 576,
                                    q_h, q_l);
    // fused (+)= zn @ Wf[:, z*576:+576]^T ; last z applies GELU into d_out
    if (z == 0)
      gemmk<EP_BIAS, 1><<<gProj, 128, 0, stream>>>(
          q_h, q_l, wf_h + z * 576, wf_l + z * 576, nullptr, nullptr, fused, bf,
          nullptr, nullptr, nullptr, 576, 3456, 576, 576, 0, 0, 0, 0.f);
    else if (z < 5)
      gemmk<EP_ACC, 1><<<gProj, 128, 0, stream>>>(
          q_h, q_l, wf_h + z * 576, wf_l + z * 576, nullptr, nullptr, fused,
          nullptr, nullptr, nullptr, nullptr, 576, 3456, 576, 576, 0, 0, 0,
          0.f);
    else
      gemmk<EP_ACCGELU, 1><<<gProj, 128, 0, stream>>>(
          q_h, q_l, wf_h + z * 576, wf_l + z * 576, nullptr, nullptr, fused,
          nullptr, nullptr, nullptr, out, 576, 3456, 576, 576, 0, 0, 0, 0.f);
  }
}

// Round 4
// 1786.697 us; speedup vs baseline: 2.6172x; 1.2242x over previous
//
#include <hip/hip_runtime.h>
#include <math.h>

#define LN_EPS 1e-5f

typedef short s8v __attribute__((ext_vector_type(8)));
typedef float f4v __attribute__((ext_vector_type(4)));

__device__ __forceinline__ short f2bf(float x) {
  union { float f; unsigned u; } v; v.f = x;
  const unsigned r = v.u + 0x7fffu + ((v.u >> 16) & 1u);
  return (short)(r >> 16);
}
__device__ __forceinline__ float bf2f(short s) {
  union { unsigned u; float f; } v;
  v.u = ((unsigned)(unsigned short)s) << 16;
  return v.f;
}

__device__ __forceinline__ void gld16(const void* g, void* l) {
  __builtin_amdgcn_global_load_lds(
      (const __attribute__((address_space(1))) void*)g,
      (__attribute__((address_space(3))) void*)l, 16, 0, 0);
}

enum { EP_SPLIT = 0, EP_SPLIT_T, EP_SIG, EP_RES, EP_BIAS, EP_ACC, EP_ACCGELU };

// Split-bf16 NT GEMM: C = A * B^T, A[M][K], B[N][K], both given as hi/lo bf16.
// 3-term MFMA per fragment (hi*hi + hi*lo + lo*hi) ~= fp32 precision.
// BM=128, BN=64*WC, BK=64, waves = 2*WC (wave-tile 64x64, 4x4 frags of 16x16x32).
// LDS rows are 128B; chunk16 index XOR (row&7) bank-swizzle applied on the
// global SOURCE address during global_load_lds staging (linear LDS dest) and
// again on the ds_read side (same involution) -> conflict-free frag reads.
//
// Grid is 1D. Logical block id l = (bid&7)*(nwg/8) + bid/8 (bijective XCD
// chunking, nwg%8==0 for every launch) is decoded panel-major:
//   pn = l % pnCnt; pm = (l/pnCnt) % pmCnt; pz = l/(pnCnt*pmCnt)
// so the pnCnt column-blocks sharing one A row-panel are consecutive logical
// ids inside ONE XCD chunk -> A panel (and per-batch B) live in that XCD's L2.
template <int EP, int WC>
__global__ __launch_bounds__(128 * WC) void gemmk(
    const short* __restrict__ Ah, const short* __restrict__ Al,
    const short* __restrict__ Bh, const short* __restrict__ Bl,
    short* __restrict__ Ch, short* __restrict__ Cl, float* __restrict__ Cf,
    const float* __restrict__ bias, const short* __restrict__ resH,
    const short* __restrict__ resL, float* __restrict__ out2, int pnCnt,
    int pmCnt, int lda, int ldb, int ldc, int K, long sA, long sB, long sC,
    float scale) {
  constexpr int BM = 128, BN = 64 * WC, T = 128 * WC;
  constexpr int RA = (BM * 128) / (T * 16);  // 16B rounds per A tensor
  constexpr int RB = (BN * 128) / (T * 16);
  __shared__ short lds[(2 * BM + 2 * BN) * 64];
  short* AsH = lds;
  short* AsL = lds + BM * 64;
  short* BsH = lds + 2 * BM * 64;
  short* BsL = lds + 2 * BM * 64 + BN * 64;

  const int tid = threadIdx.x;
  const int lane = tid & 63;
  const int wave = tid >> 6;
  const int wr = wave / WC;       // 0..1
  const int wc = wave % WC;       // 0..WC-1
  const int half = lane >> 4;     // 0..3
  const int l15 = lane & 15;

  // --- XCD-chunked panel-major block decode ---
  const int chunk = gridDim.x >> 3;
  const int l = ((int)blockIdx.x & 7) * chunk + ((int)blockIdx.x >> 3);
  const int pn = l % pnCnt;
  const int t1 = l / pnCnt;
  const int pm = t1 % pmCnt;
  const long zb = t1 / pmCnt;
  const int bm = pm * BM;
  const int bn = pn * BN;

  Ah += zb * sA; Al += zb * sA;
  Bh += zb * sB; Bl += zb * sB;

  f4v acc[4][4];
#pragma unroll
  for (int i = 0; i < 4; ++i)
#pragma unroll
    for (int j = 0; j < 4; ++j)
#pragma unroll
      for (int r = 0; r < 4; ++r) acc[i][j][r] = 0.f;

  for (int k0 = 0; k0 < K; k0 += 64) {
    __syncthreads();  // protect LDS from previous iteration's readers
#pragma unroll
    for (int t = 0; t < RA; ++t) {
      const int off = (t * T + tid) * 16;  // byte offset in [BM][128B] tile
      const int row = off >> 7;
      const int ke = ((((off >> 4) & 7) ^ (row & 7)) << 3);  // swizzled k-chunk
      const long ga = (long)(bm + row) * lda + k0 + ke;
      gld16(Ah + ga, (char*)AsH + off);
      gld16(Al + ga, (char*)AsL + off);
    }
#pragma unroll
    for (int t = 0; t < RB; ++t) {
      const int off = (t * T + tid) * 16;
      const int row = off >> 7;
      const int ke = ((((off >> 4) & 7) ^ (row & 7)) << 3);
      const long gb = (long)(bn + row) * ldb + k0 + ke;
      gld16(Bh + gb, (char*)BsH + off);
      gld16(Bl + gb, (char*)BsL + off);
    }
    __syncthreads();

#pragma unroll
    for (int s = 0; s < 2; ++s) {
      s8v ah[4], al[4], bh[4], bl[4];
#pragma unroll
      for (int i = 0; i < 4; ++i) {
        const int r = wr * 64 + i * 16 + l15;
        const int ad = r * 64 + ((((s << 2) + half) ^ (r & 7)) << 3);
        ah[i] = *(const s8v*)&AsH[ad];
        al[i] = *(const s8v*)&AsL[ad];
      }
#pragma unroll
      for (int j = 0; j < 4; ++j) {
        const int c = wc * 64 + j * 16 + l15;
        const int bd = c * 64 + ((((s << 2) + half) ^ (c & 7)) << 3);
        bh[j] = *(const s8v*)&BsH[bd];
        bl[j] = *(const s8v*)&BsL[bd];
      }
#pragma unroll
      for (int i = 0; i < 4; ++i)
#pragma unroll
        for (int j = 0; j < 4; ++j) {
          acc[i][j] = __builtin_amdgcn_mfma_f32_16x16x32_bf16(ah[i], bh[j],
                                                              acc[i][j], 0, 0, 0);
          acc[i][j] = __builtin_amdgcn_mfma_f32_16x16x32_bf16(ah[i], bl[j],
                                                              acc[i][j], 0, 0, 0);
          acc[i][j] = __builtin_amdgcn_mfma_f32_16x16x32_bf16(al[i], bh[j],
                                                              acc[i][j], 0, 0, 0);
        }
    }
  }

  // Epilogue. D frag: col = lane&15, row = (lane>>4)*4 + reg (m89-verified).
#pragma unroll
  for (int i = 0; i < 4; ++i) {
#pragma unroll
    for (int r = 0; r < 4; ++r) {
      const int row = bm + wr * 64 + i * 16 + half * 4 + r;
#pragma unroll
      for (int j = 0; j < 4; ++j) {
        const int col = bn + wc * 64 + j * 16 + l15;
        float x = acc[i][j][r];
        if (EP == EP_SPLIT) {
          const long idx = zb * sC + (long)row * ldc + col;
          const short h = f2bf(x);
          Ch[idx] = h;
          Cl[idx] = f2bf(x - bf2f(h));
        } else if (EP == EP_SPLIT_T) {
          // v-projection: write transposed vt[b][col][tok], row = b*1024+tok
          const long idx = ((long)(row >> 10) * 576 + col) * 1024 + (row & 1023);
          const short h = f2bf(x);
          Ch[idx] = h;
          Cl[idx] = f2bf(x - bf2f(h));
        } else if (EP == EP_SIG) {
          x = 1.f / (1.f + expf(-x * scale));
          const long idx = zb * sC + (long)row * ldc + col;
          const short h = f2bf(x);
          Ch[idx] = h;
          Cl[idx] = f2bf(x - bf2f(h));
        } else if (EP == EP_RES) {
          const long idx = (long)row * ldc + col;
          Cf[idx] = x + bias[col] + bf2f(resH[idx]) + bf2f(resL[idx]);
        } else if (EP == EP_BIAS) {
          const long idx = (long)row * ldc + col;
          Cf[idx] = x + bias[col];
        } else if (EP == EP_ACC) {
          const long idx = (long)row * ldc + col;
          Cf[idx] += x;
        } else if (EP == EP_ACCGELU) {
          const long idx = (long)row * ldc + col;
          const float sum = Cf[idx] + x;
          out2[idx] = 0.5f * sum * (1.f + erff(sum * 0.70710678118654752f));
        }
      }
    }
  }
}

// LayerNorm over C=576, writes hi/lo bf16 split. One 576-thread block per row.
__global__ __launch_bounds__(576) void ln576(const float* __restrict__ x,
                                             const float* __restrict__ g,
                                             const float* __restrict__ b,
                                             short* __restrict__ oh,
                                             short* __restrict__ ol) {
  __shared__ float red[2][9];
  __shared__ float mu_s, rs_s;
  const long row = blockIdx.x;
  const int t = threadIdx.x;
  const float v = x[row * 576 + t];
  float s = v, s2 = v * v;
#pragma unroll
  for (int off = 32; off > 0; off >>= 1) {
    s += __shfl_xor(s, off);
    s2 += __shfl_xor(s2, off);
  }
  if ((t & 63) == 0) {
    red[0][t >> 6] = s;
    red[1][t >> 6] = s2;
  }
  __syncthreads();
  if (t == 0) {
    float a = 0.f, a2 = 0.f;
#pragma unroll
    for (int i = 0; i < 9; ++i) {
      a += red[0][i];
      a2 += red[1][i];
    }
    const float mu = a * (1.f / 576.f);
    mu_s = mu;
    rs_s = rsqrtf(a2 * (1.f / 576.f) - mu * mu + LN_EPS);
  }
  __syncthreads();
  const float y = (v - mu_s) * rs_s * g[t] + b[t];
  const short h = f2bf(y);
  oh[row * 576 + t] = h;
  ol[row * 576 + t] = f2bf(y - bf2f(h));
}

// fp32 -> (hi,lo) bf16 split, elementwise.
__global__ __launch_bounds__(256) void splitk(const float* __restrict__ in,
                                              short* __restrict__ oh,
                                              short* __restrict__ ol, long n) {
  long i = (long)blockIdx.x * blockDim.x + threadIdx.x;
  const long stride = (long)gridDim.x * blockDim.x;
  for (; i < n; i += stride) {
    const float x = in[i];
    const short h = f2bf(x);
    oh[i] = h;
    ol[i] = f2bf(x - bf2f(h));
  }
}

extern "C" void kernel_launch(void* const* d_in, const int* in_sizes, int n_in,
                              void* d_out, int out_size, void* d_ws,
                              size_t ws_size, hipStream_t stream) {
  const float* img = (const float*)d_in[0];
  const float* aolp = (const float*)d_in[1];
  const float* dolp = (const float*)d_in[2];
  const float* lnx_g = (const float*)d_in[3];
  const float* lnx_b = (const float*)d_in[4];
  const float* lny_g = (const float*)d_in[5];
  const float* lny_b = (const float*)d_in[6];
  const float* lnz_g = (const float*)d_in[7];
  const float* lnz_b = (const float*)d_in[8];
  const float* Wq = (const float*)d_in[9];
  const float* Wk = (const float*)d_in[10];
  const float* Wv = (const float*)d_in[11];
  const float* Wp = (const float*)d_in[12];
  const float* bp = (const float*)d_in[13];
  const float* Wf = (const float*)d_in[14];
  const float* bf = (const float*)d_in[15];
  float* out = (float*)d_out;

  const long S = 8L * 1024 * 576;   // 4,718,592
  const long W = 6L * 576 * 576;    // 1,990,656 (also == 576*3456)
  char* p = (char*)d_ws;
  auto alloc = [&](long bytes) {
    char* r = p;
    p += (bytes + 255) & ~255L;
    return r;
  };
  short* xn_h = (short*)alloc(S * 2);
  short* xn_l = (short*)alloc(S * 2);
  short* yn_h = (short*)alloc(S * 2);  // also o after AV
  short* yn_l = (short*)alloc(S * 2);
  short* q_h = (short*)alloc(S * 2);   // also z after LNz
  short* q_l = (short*)alloc(S * 2);
  short* k_h = (short*)alloc(S * 2);
  short* k_l = (short*)alloc(S * 2);
  short* vt_h = (short*)alloc(S * 2);  // [8][576][1024]
  short* vt_l = (short*)alloc(S * 2);
  short* attn_h = (short*)alloc(8L * 1024 * 1024 * 2 * 2);  // hi then lo
  short* attn_l = attn_h + 8L * 1024 * 1024;
  float* t_f32 = (float*)attn_h;  // aliases attn (dead after AV); 18.9<=33.5MB
  float* fused = (float*)alloc(S * 4);
  short* wq_h = (short*)alloc(W * 2);
  short* wq_l = (short*)alloc(W * 2);
  short* wk_h = (short*)alloc(W * 2);
  short* wk_l = (short*)alloc(W * 2);
  short* wv_h = (short*)alloc(W * 2);
  short* wv_l = (short*)alloc(W * 2);
  short* wp_h = (short*)alloc(W * 2);
  short* wp_l = (short*)alloc(W * 2);
  short* wf_h = (short*)alloc(W * 2);
  short* wf_l = (short*)alloc(W * 2);

  // weight splits (re-done every call; ws is re-poisoned)
  splitk<<<1024, 256, 0, stream>>>(Wq, wq_h, wq_l, W);
  splitk<<<1024, 256, 0, stream>>>(Wk, wk_h, wk_l, W);
  splitk<<<1024, 256, 0, stream>>>(Wv, wv_h, wv_l, W);
  splitk<<<1024, 256, 0, stream>>>(Wp, wp_h, wp_l, W);
  splitk<<<1024, 256, 0, stream>>>(Wf, wf_h, wf_l, W);

  const float* src[3] = {img, aolp, dolp};
  const int xi[6] = {0, 0, 1, 1, 2, 2};
  const int yi[6] = {1, 2, 0, 2, 0, 1};
  const float scale = 1.f / 24.f;  // 576^-0.5

  // 1D grids (all multiples of 8 -> bijective XCD chunking)
  const int nProj = 9 * 64;      // pn=9 (N=576/64), pm=64 (M=8192/128) -> 576
  const int nScore = 8 * 8 * 8;  // pn=8, pm=8, pz=8 -> 512
  const int nAV = 9 * 8 * 8;     // pn=9, pm=8, pz=8 -> 576

  for (int z = 0; z < 6; ++z) {
    const long wo = (long)z * 576 * 576;
    ln576<<<8192, 576, 0, stream>>>(src[xi[z]], lnx_g + z * 576,
                                    lnx_b + z * 576, xn_h, xn_l);
    ln576<<<8192, 576, 0, stream>>>(src[yi[z]], lny_g + z * 576,
                                    lny_b + z * 576, yn_h, yn_l);
    // q = LN(y) @ Wq^T   k = LN(x) @ Wk^T   vt = (LN(x) @ Wv^T)^T
    gemmk<EP_SPLIT, 1><<<nProj, 128, 0, stream>>>(
        yn_h, yn_l, wq_h + wo, wq_l + wo, q_h, q_l, nullptr, nullptr, nullptr,
        nullptr, nullptr, 9, 64, 576, 576, 576, 576, 0, 0, 0, 0.f);
    gemmk<EP_SPLIT, 1><<<nProj, 128, 0, stream>>>(
        xn_h, xn_l, wk_h + wo, wk_l + wo, k_h, k_l, nullptr, nullptr, nullptr,
        nullptr, nullptr, 9, 64, 576, 576, 576, 576, 0, 0, 0, 0.f);
    gemmk<EP_SPLIT_T, 1><<<nProj, 128, 0, stream>>>(
        xn_h, xn_l, wv_h + wo, wv_l + wo, vt_h, vt_l, nullptr, nullptr, nullptr,
        nullptr, nullptr, 9, 64, 576, 576, 0, 576, 0, 0, 0, 0.f);
    // attn = sigmoid(q @ k^T * scale), per batch (XCD chunk == one batch)
    gemmk<EP_SIG, 2><<<nScore, 256, 0, stream>>>(
        q_h, q_l, k_h, k_l, attn_h, attn_l, nullptr, nullptr, nullptr, nullptr,
        nullptr, 8, 8, 576, 576, 1024, 576, 1024L * 576, 1024L * 576,
        1024L * 1024, scale);
    // o = attn @ vt^T, per batch (into yn buffers)
    gemmk<EP_SPLIT, 1><<<nAV, 128, 0, stream>>>(
        attn_h, attn_l, vt_h, vt_l, yn_h, yn_l, nullptr, nullptr, nullptr,
        nullptr, nullptr, 9, 8, 1024, 1024, 576, 1024, 1024L * 1024,
        576L * 1024, 1024L * 576, 0.f);
    // t = o @ Wp^T + bp + xn  (fp32, into attn-aliased buffer)
    gemmk<EP_RES, 1><<<nProj, 128, 0, stream>>>(
        yn_h, yn_l, wp_h + wo, wp_l + wo, nullptr, nullptr, t_f32, bp + z * 576,
        xn_h, xn_l, nullptr, 9, 64, 576, 576, 576, 576, 0, 0, 0, 0.f);
    // zn = LN(t) (into q buffers)
    ln576<<<8192, 576, 0, stream>>>(t_f32, lnz_g + z * 576, lnz_b + z * 576,
                                    q_h, q_l);
    // fused (+)= zn @ Wf[:, z*576:+576]^T ; last z applies GELU into d_out
    if (z == 0)
      gemmk<EP_BIAS, 1><<<nProj, 128, 0, stream>>>(
          q_h, q_l, wf_h + z * 576, wf_l + z * 576, nullptr, nullptr, fused, bf,
          nullptr, nullptr, nullptr, 9, 64, 576, 3456, 576, 576, 0, 0, 0, 0.f);
    else if (z < 5)
      gemmk<EP_ACC, 1><<<nProj, 128, 0, stream>>>(
          q_h, q_l, wf_h + z * 576, wf_l + z * 576, nullptr, nullptr, fused,
          nullptr, nullptr, nullptr, nullptr, 9, 64, 576, 3456, 576, 576, 0, 0,
          0, 0.f);
    else
      gemmk<EP_ACCGELU, 1><<<nProj, 128, 0, stream>>>(
          q_h, q_l, wf_h + z * 576, wf_l + z * 576, nullptr, nullptr, fused,
          nullptr, nullptr, nullptr, out, 9, 64, 576, 3456, 576, 576, 0, 0, 0,
          0.f);
  }
}